// Round 8
// baseline (1825.098 us; speedup 1.0000x reference)
//
#include <hip/hip_runtime.h>
#include <math.h>

#define B_   64
#define S_   1024
#define DK_  128
#define DV_  128
#define LR_    0.1f
#define THR_   0.1f
#define ITEMP_ 10.0f   // 1/temperature
#define EPS_   1e-6f

// ---- DPP helpers ----
template<int CTRL>
__device__ __forceinline__ float dpp_add(float x) {
  int t = __builtin_amdgcn_update_dpp(0, __float_as_int(x), CTRL, 0xf, 0xf, true);
  return x + __int_as_float(t);
}
__device__ __forceinline__ float wave_sum64(float x) {
  x = dpp_add<0x111>(x); // row_shr:1
  x = dpp_add<0x112>(x); // row_shr:2
  x = dpp_add<0x114>(x); // row_shr:4
  x = dpp_add<0x118>(x); // row_shr:8
  x = dpp_add<0x142>(x); // row_bcast:15
  x = dpp_add<0x143>(x); // row_bcast:31
  return __int_as_float(__builtin_amdgcn_readlane(__float_as_int(x), 63));
}
// quad butterfly: after both, all 4 lanes of each quad hold the quad sum
__device__ __forceinline__ float quad_sum4(float x) {
  x = dpp_add<0xB1>(x);  // quad_perm [1,0,3,2]  (xor 1)
  x = dpp_add<0x4E>(x);  // quad_perm [2,3,0,1]  (xor 2)
  return x;
}

__global__ __launch_bounds__(512, 2)
void sgm_kernel(const float* __restrict__ mem_in,
                const float* __restrict__ key,
                const float* __restrict__ value,
                float* __restrict__ out) {
  const int b    = blockIdx.x;
  const int tid  = threadIdx.x;
  const int r    = tid >> 2;         // row 0..127
  const int q    = tid & 3;          // column quarter
  const int col0 = q * 32;
  const int lane = tid & 63;
  const int wv   = tid >> 6;         // wave 0..7

  __shared__ float4 red[2][2];       // per-parity 8 wave partials

  // ---- memory state: 32 floats/thread ----
  float m[32];
  {
    const float* mp = mem_in + ((size_t)b * DV_ + r) * DK_ + col0;
    #pragma unroll
    for (int i = 0; i < 8; ++i) {
      float4 t = reinterpret_cast<const float4*>(mp)[i];
      m[4*i+0]=t.x; m[4*i+1]=t.y; m[4*i+2]=t.z; m[4*i+3]=t.w;
    }
  }

  const float* kbase = key   + (size_t)b * S_ * DK_;
  const float* vbase = value + (size_t)b * S_ * DV_;
  float*       gout  = out + (size_t)B_ * DV_ * DK_ + (size_t)b * S_;

  float kA[32], kB[32];
  float kaA, kbA, vA, kaB, kbB, vB;
  float c1 = 0.f, u1 = 0.f;   // pending update: c1 = g_{s-1}*rin_{s-1}, u1 = u_{s-1}[r]

  // prologue: k_0 -> A ; B := 0 (k_{-1})
  #pragma unroll
  for (int i = 0; i < 32; ++i) kB[i] = 0.f;
  kaB = 0.f; kbB = 0.f; vB = 0.f;
  {
    kaA = kbase[lane]; kbA = kbase[64 + lane]; vA = vbase[r];
    const float* kp = kbase + col0;
    #pragma unroll
    for (int i = 0; i < 8; ++i) {
      float4 t = reinterpret_cast<const float4*>(kp)[i];
      kA[4*i+0]=t.x; kA[4*i+1]=t.y; kA[4*i+2]=t.z; kA[4*i+3]=t.w;
    }
  }

  // Entry: m = M_{s-2}; kC = k_s; kO = k_{s-1} (pending update c1,u1).
  // Exit: m = M_{s-1}; k_{s+1} prefetched into kO; c1,u1 = step-s pending.
  auto half = [&](int s, float (&kC)[32], float (&kO)[32],
                  float& kaC, float& kbC, float& vC,
                  float& kaO, float& kbO, float& vO) {
    const float rinC = 1.0f / (sqrtf(wave_sum64(kaC*kaC + kbC*kbC)) + EPS_);
    const float dkOC = wave_sum64(kaO*kaC + kbO*kbC);   // k_{s-1}.k_s (raw)

    // matvec on stale m (= M_{s-2}) with raw k_s: 32 FMA, 4 accumulators
    float d0=0.f, d1=0.f, d2=0.f, d3=0.f;
    #pragma unroll
    for (int i = 0; i < 32; i += 4) {
      d0 = fmaf(m[i+0], kC[i+0], d0);
      d1 = fmaf(m[i+1], kC[i+1], d1);
      d2 = fmaf(m[i+2], kC[i+2], d2);
      d3 = fmaf(m[i+3], kC[i+3], d3);
    }
    const float rawf = quad_sum4((d0 + d1) + (d2 + d3)); // full row dot in all 4 quad lanes

    // pred = rinC*(raw - c1*dkOC*u1)   [exact delta-rule correction]
    const float pred  = rinC * fmaf(-(c1 * dkOC), u1, rawf);
    const float surp  = pred - vC;
    const float usnew = fmaf(LR_, surp, pred);
    const float tot   = wave_sum64(surp * surp);  // 4x row duplication

    if (lane == 0) ((float*)&red[s & 1][0])[wv] = tot;

    // pending rank-1 update for step s-1 (indep. of this step's gate)
    const float a1 = c1 * u1;
    #pragma unroll
    for (int i = 0; i < 32; ++i) m[i] = fmaf(-a1, kO[i], m[i]);

    // prefetch step s+1 into O (kO consumed above)
    const int sn = (s + 1 < S_) ? (s + 1) : (S_ - 1);
    {
      const float* kp = kbase + (size_t)sn * DK_;
      kaO = kp[lane]; kbO = kp[64 + lane]; vO = vbase[(size_t)sn * DV_ + r];
      const float* kpc = kp + col0;
      #pragma unroll
      for (int i = 0; i < 8; ++i) {
        float4 t = reinterpret_cast<const float4*>(kpc)[i];
        kO[4*i+0]=t.x; kO[4*i+1]=t.y; kO[4*i+2]=t.z; kO[4*i+3]=t.w;
      }
    }

    asm volatile("s_waitcnt lgkmcnt(0)" ::: "memory");  // LDS write visible
    __builtin_amdgcn_s_barrier();                       // vmcnt stays in flight
    asm volatile("" ::: "memory");
    const float4 q0 = red[s & 1][0];
    const float4 q1 = red[s & 1][1];
    const float s2  = 0.25f * (((q0.x + q0.y) + (q0.z + q0.w)) +
                               ((q1.x + q1.y) + (q1.z + q1.w)));
    const float g   = 1.0f / (1.0f + __expf((THR_ - sqrtf(s2)) * ITEMP_));
    if (tid == 0) gout[s] = g;

    c1 = g * rinC;
    u1 = usnew;
  };

  for (int s = 0; s < S_; s += 2) {
    half(s,     kA, kB, kaA, kbA, vA, kaB, kbB, vB);
    half(s + 1, kB, kA, kaB, kbB, vB, kaA, kbA, vA);
  }

  // final pending update for step S-1 (k_{1023} lives in kB)
  {
    const float a1 = c1 * u1;
    #pragma unroll
    for (int i = 0; i < 32; ++i) m[i] = fmaf(-a1, kB[i], m[i]);
  }

  float* op = out + ((size_t)b * DV_ + r) * DK_ + col0;
  #pragma unroll
  for (int i = 0; i < 8; ++i) {
    float4 t = make_float4(m[4*i+0], m[4*i+1], m[4*i+2], m[4*i+3]);
    reinterpret_cast<float4*>(op)[i] = t;
  }
}

extern "C" void kernel_launch(void* const* d_in, const int* in_sizes, int n_in,
                              void* d_out, int out_size, void* d_ws, size_t ws_size,
                              hipStream_t stream) {
  const float* mem = (const float*)d_in[0];
  const float* key = (const float*)d_in[1];
  const float* val = (const float*)d_in[2];
  float* out = (float*)d_out;
  sgm_kernel<<<B_, 512, 0, stream>>>(mem, key, val, out);
}

// Round 9
// 1219.565 us; speedup vs baseline: 1.4965x; 1.4965x over previous
//
#include <hip/hip_runtime.h>
#include <math.h>

#define B_   64
#define S_   1024
#define DK_  128
#define DV_  128
#define LR_    0.1f
#define THR_   0.1f
#define ITEMP_ 10.0f   // 1/temperature
#define EPS_   1e-6f

// ---- DPP wave reduction helpers ----
template<int CTRL>
__device__ __forceinline__ float dpp_add(float x) {
  int t = __builtin_amdgcn_update_dpp(0, __float_as_int(x), CTRL, 0xf, 0xf, true);
  return x + __int_as_float(t);
}
__device__ __forceinline__ float wave_sum64(float x) {
  x = dpp_add<0x111>(x); // row_shr:1
  x = dpp_add<0x112>(x); // row_shr:2
  x = dpp_add<0x114>(x); // row_shr:4
  x = dpp_add<0x118>(x); // row_shr:8
  x = dpp_add<0x142>(x); // row_bcast:15
  x = dpp_add<0x143>(x); // row_bcast:31
  return __int_as_float(__builtin_amdgcn_readlane(__float_as_int(x), 63));
}
__device__ __forceinline__ float pair_sum(float x) { // lanes 2j <-> 2j+1 combine
  int t = __builtin_amdgcn_update_dpp(0, __float_as_int(x), 0xB1, 0xf, 0xf, true);
  return x + __int_as_float(t);
}

// ---- async global -> LDS (direct, no VGPR round trip) ----
__device__ __forceinline__ void gll16(const float* g, float* l) {
  __builtin_amdgcn_global_load_lds(
      (const __attribute__((address_space(1))) unsigned int*)g,
      (__attribute__((address_space(3))) unsigned int*)l, 16, 0, 0);
}
__device__ __forceinline__ void gll4(const float* g, float* l) {
  __builtin_amdgcn_global_load_lds(
      (const __attribute__((address_space(1))) unsigned int*)g,
      (__attribute__((address_space(3))) unsigned int*)l, 4, 0, 0);
}

__global__ __launch_bounds__(256, 1)
void sgm_kernel(const float* __restrict__ mem_in,
                const float* __restrict__ key,
                const float* __restrict__ value,
                float* __restrict__ out) {
  const int b    = blockIdx.x;
  const int tid  = threadIdx.x;
  const int r    = tid >> 1;          // row 0..127
  const int col0 = (tid & 1) * 64;    // column half
  const int lane = tid & 63;
  const int wv   = tid >> 6;          // wave 0..3
  const int rl   = (tid >> 1) & 31;   // row within this wave's 32-row group

  __shared__ float ldsK[4][4][DK_];   // [wave][depth4][128]  (per-wave copy)
  __shared__ float ldsV[4][4][32];    // [wave][depth4][wave's 32 rows]
  __shared__ float slotS[2][4];       // parity x wave partials
  __shared__ float gateL[S_];         // gates, written by tid0, flushed at end

  // ---- memory state: 64 floats/thread ----
  float m[64];
  {
    const float* mp = mem_in + ((size_t)b * DV_ + r) * DK_ + col0;
    #pragma unroll
    for (int i = 0; i < 16; ++i) {
      float4 t = reinterpret_cast<const float4*>(mp)[i];
      m[4*i+0]=t.x; m[4*i+1]=t.y; m[4*i+2]=t.z; m[4*i+3]=t.w;
    }
  }

  const float* kb = key   + (size_t)b * S_ * DK_;
  const float* vb = value + (size_t)b * S_ * DV_;

  // zero k_{-1} slot (depth 3) — read by step 0's pending update (coef 0, NaN-safety)
  ldsK[wv][3][lane] = 0.f;
  ldsK[wv][3][64 + lane] = 0.f;

  // prologue: prefetch steps 0 and 1 (2 vmem ops per step per wave)
  if (lane < 32) {
    gll16(kb + 0*DK_ + lane*4, &ldsK[wv][0][0]);
    gll4 (vb + 0*DV_ + wv*32 + lane, &ldsV[wv][0][0]);
    gll16(kb + 1*DK_ + lane*4, &ldsK[wv][1][0]);
    gll4 (vb + 1*DV_ + wv*32 + lane, &ldsV[wv][1][0]);
  }

  float c1 = 0.f, u1 = 0.f;     // pending update scalars (step s-1)
  float kaO = 0.f, kbO = 0.f;   // k_{s-1} lane-elements for the dk dot

  for (int s = 0; s < S_; ++s) {
    // prefetch step s+2 (clamped reload of 1023 is identical data -> harmless)
    const int sp2 = (s + 2 < S_) ? s + 2 : S_ - 1;
    if (lane < 32) {
      gll16(kb + (size_t)sp2*DK_ + lane*4, &ldsK[wv][sp2 & 3][0]);
      gll4 (vb + (size_t)sp2*DV_ + wv*32 + lane, &ldsV[wv][sp2 & 3][0]);
    }
    // step-s buffers ready; s+1 & s+2 (4 loads) stay in flight
    asm volatile("s_waitcnt vmcnt(4)" ::: "memory");

    const int cs = s & 3;         // slot of k_s / v_s
    const int ps = (s + 3) & 3;   // slot of k_{s-1}

    const float kaC = ldsK[wv][cs][lane];
    const float kbC = ldsK[wv][cs][64 + lane];
    const float vC  = ldsV[wv][cs][rl];
    const float rin = 1.0f / (sqrtf(wave_sum64(kaC*kaC + kbC*kbC)) + EPS_);
    const float dk  = wave_sum64(kaO*kaC + kbO*kbC);   // raw k_{s-1}.k_s

    // matvec on stale m (= M_{s-2}) with raw k_s, streamed from LDS
    const float4* kc = reinterpret_cast<const float4*>(&ldsK[wv][cs][col0]);
    float d0=0.f, d1=0.f, d2=0.f, d3=0.f;
    #pragma unroll
    for (int i = 0; i < 16; ++i) {
      float4 t = kc[i];
      d0 = fmaf(m[4*i+0], t.x, d0);
      d1 = fmaf(m[4*i+1], t.y, d1);
      d2 = fmaf(m[4*i+2], t.z, d2);
      d3 = fmaf(m[4*i+3], t.w, d3);
    }
    const float raw = pair_sum((d0 + d1) + (d2 + d3)); // full-row dot, both pair lanes

    // pred = rin*(raw - c1*dk*u1)  [exact lag-1 delta-rule correction]
    const float pred = rin * fmaf(-(c1 * dk), u1, raw);
    const float surp = pred - vC;
    const float ws   = wave_sum64(surp * surp);  // 2x wave partial (pair duplication)
    if (lane == 0) slotS[s & 1][wv] = ws;

    // pending rank-1 update (step s-1) fills the barrier window; streams k_{s-1}
    const float a1 = c1 * u1;
    const float4* kp = reinterpret_cast<const float4*>(&ldsK[wv][ps][col0]);
    #pragma unroll
    for (int i = 0; i < 16; ++i) {
      float4 t = kp[i];
      m[4*i+0] = fmaf(-a1, t.x, m[4*i+0]);
      m[4*i+1] = fmaf(-a1, t.y, m[4*i+1]);
      m[4*i+2] = fmaf(-a1, t.z, m[4*i+2]);
      m[4*i+3] = fmaf(-a1, t.w, m[4*i+3]);
    }

    asm volatile("s_waitcnt lgkmcnt(0)" ::: "memory"); // slot write + ds_reads retired
    __builtin_amdgcn_s_barrier();                      // raw: vmcnt stays in flight
    asm volatile("" ::: "memory");

    const float s2 = 0.5f * ((slotS[s&1][0] + slotS[s&1][1]) +
                             (slotS[s&1][2] + slotS[s&1][3])); // fixed order
    const float g  = 1.0f / (1.0f + __expf((THR_ - sqrtf(s2)) * ITEMP_));
    if (tid == 0) gateL[s] = g;

    c1 = g * rin;
    u1 = fmaf(LR_, surp, pred);
    kaO = kaC; kbO = kbC;
  }

  // final pending update (step S-1): k_{1023} lives in slot 3
  {
    const float a1 = c1 * u1;
    const float4* kp = reinterpret_cast<const float4*>(&ldsK[wv][3][col0]);
    #pragma unroll
    for (int i = 0; i < 16; ++i) {
      float4 t = kp[i];
      m[4*i+0] = fmaf(-a1, t.x, m[4*i+0]);
      m[4*i+1] = fmaf(-a1, t.y, m[4*i+1]);
      m[4*i+2] = fmaf(-a1, t.z, m[4*i+2]);
      m[4*i+3] = fmaf(-a1, t.w, m[4*i+3]);
    }
  }

  __syncthreads();  // gates visible; outstanding glls drained (loop is done)

  // write final memory
  float* op = out + ((size_t)b * DV_ + r) * DK_ + col0;
  #pragma unroll
  for (int i = 0; i < 16; ++i) {
    float4 t = make_float4(m[4*i+0], m[4*i+1], m[4*i+2], m[4*i+3]);
    reinterpret_cast<float4*>(op)[i] = t;
  }
  // write gates (256 threads x float4 = 1024)
  float* go = out + (size_t)B_ * DV_ * DK_ + (size_t)b * S_;
  reinterpret_cast<float4*>(go)[tid] = reinterpret_cast<const float4*>(gateL)[tid];
}

extern "C" void kernel_launch(void* const* d_in, const int* in_sizes, int n_in,
                              void* d_out, int out_size, void* d_ws, size_t ws_size,
                              hipStream_t stream) {
  const float* mem = (const float*)d_in[0];
  const float* key = (const float*)d_in[1];
  const float* val = (const float*)d_in[2];
  float* out = (float*)d_out;
  sgm_kernel<<<B_, 256, 0, stream>>>(mem, key, val, out);
}

// Round 10
// 1025.102 us; speedup vs baseline: 1.7804x; 1.1897x over previous
//
#include <hip/hip_runtime.h>
#include <math.h>

#define B_   64
#define S_   1024
#define DK_  128
#define DV_  128
#define LR_    0.1f
#define THR_   0.1f
#define ITEMP_ 10.0f   // 1/temperature
#define EPS_   1e-6f

// ---- DPP wave reduction helpers ----
template<int CTRL>
__device__ __forceinline__ float dpp_add(float x) {
  int t = __builtin_amdgcn_update_dpp(0, __float_as_int(x), CTRL, 0xf, 0xf, true);
  return x + __int_as_float(t);
}
__device__ __forceinline__ float wave_sum64(float x) {
  x = dpp_add<0x111>(x); // row_shr:1
  x = dpp_add<0x112>(x); // row_shr:2
  x = dpp_add<0x114>(x); // row_shr:4
  x = dpp_add<0x118>(x); // row_shr:8
  x = dpp_add<0x142>(x); // row_bcast:15
  x = dpp_add<0x143>(x); // row_bcast:31
  return __int_as_float(__builtin_amdgcn_readlane(__float_as_int(x), 63));
}
__device__ __forceinline__ float pair_sum(float x) { // 2j <-> 2j+1
  int t = __builtin_amdgcn_update_dpp(0, __float_as_int(x), 0xB1, 0xf, 0xf, true);
  return x + __int_as_float(t);
}

// ---- async global -> LDS ----
__device__ __forceinline__ void gll16(const float* g, float* l) {
  __builtin_amdgcn_global_load_lds(
      (const __attribute__((address_space(1))) unsigned int*)g,
      (__attribute__((address_space(3))) unsigned int*)l, 16, 0, 0);
}
__device__ __forceinline__ void gll4(const float* g, float* l) {
  __builtin_amdgcn_global_load_lds(
      (const __attribute__((address_space(1))) unsigned int*)g,
      (__attribute__((address_space(3))) unsigned int*)l, 4, 0, 0);
}

__global__ __launch_bounds__(256, 1)
void sgm_kernel(const float* __restrict__ mem_in,
                const float* __restrict__ key,
                const float* __restrict__ value,
                float* __restrict__ out) {
  const int b    = blockIdx.x;
  const int tid  = threadIdx.x;
  const int r    = tid >> 1;        // row 0..127
  const int h    = tid & 1;         // interleaved half: owns float4 chunks 2i+h
  const int lane = tid & 63;
  const int wv   = tid >> 6;
  const int rl   = (tid >> 1) & 31;

  __shared__ float  ldsK[4][4][DK_];   // [wave][depth4][128]
  __shared__ float  ldsV[4][4][32];
  __shared__ float4 slotS[2];          // [parity] -> 4 wave partials
  __shared__ float  gateL[S_];

  // m interleaved: m[4i..4i+3] = row's float4 chunk (2i+h)
  float m[64], kE[64], kO[64];
  {
    const float4* mp4 = reinterpret_cast<const float4*>(mem_in + ((size_t)b*DV_ + r)*DK_);
    #pragma unroll
    for (int i = 0; i < 16; ++i) {
      float4 t = mp4[2*i + h];
      m[4*i+0]=t.x; m[4*i+1]=t.y; m[4*i+2]=t.z; m[4*i+3]=t.w;
    }
  }
  #pragma unroll
  for (int i = 0; i < 64; ++i) kE[i] = 0.f;   // acts as k_{-1} (a1=0, NaN-safe)

  const float* kb = key   + (size_t)b * S_ * DK_;
  const float* vb = value + (size_t)b * S_ * DV_;

  // prologue: prefetch steps 0,1
  if (lane < 32) {
    gll16(kb + 0*DK_ + lane*4, &ldsK[wv][0][0]);
    gll4 (vb + 0*DV_ + wv*32 + lane, &ldsV[wv][0][0]);
    gll16(kb + 1*DK_ + lane*4, &ldsK[wv][1][0]);
    gll4 (vb + 1*DV_ + wv*32 + lane, &ldsV[wv][1][0]);
  }
  asm volatile("s_waitcnt vmcnt(2)" ::: "memory");   // k0,v0 resident

  float kaC = ldsK[wv][0][lane], kbC = ldsK[wv][0][64+lane];
  float vCur = ldsV[wv][0][rl];
  float rinCur = 1.0f / (sqrtf(wave_sum64(kaC*kaC + kbC*kbC)) + EPS_);
  float rawCur;
  {
    const float4* kp4 = reinterpret_cast<const float4*>(&ldsK[wv][0][0]);
    float d0=0,d1=0,d2=0,d3=0;
    #pragma unroll
    for (int i = 0; i < 16; ++i) {
      float4 t = kp4[2*i + h];
      kO[4*i+0]=t.x; kO[4*i+1]=t.y; kO[4*i+2]=t.z; kO[4*i+3]=t.w;  // k_0 for step1 update
      d0=fmaf(m[4*i+0],t.x,d0); d1=fmaf(m[4*i+1],t.y,d1);
      d2=fmaf(m[4*i+2],t.z,d2); d3=fmaf(m[4*i+3],t.w,d3);
    }
    rawCur = pair_sum((d0+d1)+(d2+d3));   // M_init . k_0 (raw)
  }
  float dkCur = 0.f, u1 = 0.f, gPrev = 0.f, rinPrev = 0.f;

  // step s: entry rawCur = M_{s-2}.k_s (raw), buf = k_{s-1}; exit buf = k_{s+1}
  auto half = [&](int s, float (&buf)[64]) {
    const int sp2 = (s + 2 < S_) ? s + 2 : S_ - 1;
    if (lane < 32) {
      gll16(kb + (size_t)sp2*DK_ + lane*4, &ldsK[wv][sp2&3][0]);
      gll4 (vb + (size_t)sp2*DV_ + wv*32 + lane, &ldsV[wv][sp2&3][0]);
    }
    // ---- gate-chain head (short): depends only on gPrev ----
    const float c1   = gPrev * rinPrev;
    const float pred = rinCur * fmaf(-(c1 * dkCur), u1, rawCur);
    const float surp = pred - vCur;
    const float ws   = wave_sum64(surp * surp);
    if (lane == 0) ((float*)&slotS[s & 1])[wv] = ws;
    const float uNew = fmaf(LR_, surp, pred);

    // ---- bulk: register-only update for step s-1 ----
    const float a1 = c1 * u1;
    #pragma unroll
    for (int i = 0; i < 64; ++i) m[i] = fmaf(-a1, buf[i], m[i]);

    asm volatile("s_waitcnt vmcnt(2)" ::: "memory");  // k_{s+1},v_{s+1} resident
    const int ns = (s + 1) & 3;
    const float kaN = ldsK[wv][ns][lane], kbN = ldsK[wv][ns][64+lane];
    const float vN  = ldsV[wv][ns][rl];
    const float dkN  = wave_sum64(kaC*kaN + kbC*kbN);
    const float rinN = 1.0f / (sqrtf(wave_sum64(kaN*kaN + kbN*kbN)) + EPS_);

    // matvec raw_{s+1} = M_{s-1}.k_{s+1}; save k_{s+1} into buf
    const float4* kp4 = reinterpret_cast<const float4*>(&ldsK[wv][ns][0]);
    float d0=0,d1=0,d2=0,d3=0;
    #pragma unroll
    for (int i = 0; i < 16; ++i) {
      float4 t = kp4[2*i + h];                       // disjoint-bank broadcast
      buf[4*i+0]=t.x; buf[4*i+1]=t.y; buf[4*i+2]=t.z; buf[4*i+3]=t.w;
      d0=fmaf(m[4*i+0],t.x,d0); d1=fmaf(m[4*i+1],t.y,d1);
      d2=fmaf(m[4*i+2],t.z,d2); d3=fmaf(m[4*i+3],t.w,d3);
    }
    const float rawN = pair_sum((d0+d1)+(d2+d3));

    asm volatile("s_waitcnt lgkmcnt(0)" ::: "memory");
    __builtin_amdgcn_s_barrier();                    // vmcnt stays in flight
    asm volatile("" ::: "memory");
    const float4 qv = slotS[s & 1];
    const float s2  = 0.5f * ((qv.x + qv.y) + (qv.z + qv.w)); // fixed order
    const float g   = 1.0f / (1.0f + __expf((THR_ - sqrtf(s2)) * ITEMP_));
    if (tid == 0) gateL[s] = g;

    gPrev = g; rinPrev = rinCur; rinCur = rinN; dkCur = dkN; rawCur = rawN;
    u1 = uNew; kaC = kaN; kbC = kbN; vCur = vN;
  };

  for (int s = 0; s < S_; s += 2) { half(s, kE); half(s + 1, kO); }

  // pending update for step S-1: k_{1023} from LDS slot 3 (buf was clobbered by clamp)
  {
    const float a1 = (gPrev * rinPrev) * u1;
    const float4* kp4 = reinterpret_cast<const float4*>(&ldsK[wv][3][0]);
    #pragma unroll
    for (int i = 0; i < 16; ++i) {
      float4 t = kp4[2*i + h];
      m[4*i+0]=fmaf(-a1,t.x,m[4*i+0]); m[4*i+1]=fmaf(-a1,t.y,m[4*i+1]);
      m[4*i+2]=fmaf(-a1,t.z,m[4*i+2]); m[4*i+3]=fmaf(-a1,t.w,m[4*i+3]);
    }
  }

  __syncthreads();

  float4* op4 = reinterpret_cast<float4*>(out + ((size_t)b*DV_ + r)*DK_);
  #pragma unroll
  for (int i = 0; i < 16; ++i)
    op4[2*i + h] = make_float4(m[4*i+0], m[4*i+1], m[4*i+2], m[4*i+3]);

  float* go = out + (size_t)B_ * DV_ * DK_ + (size_t)b * S_;
  reinterpret_cast<float4*>(go)[tid] = reinterpret_cast<const float4*>(gateL)[tid];
}

extern "C" void kernel_launch(void* const* d_in, const int* in_sizes, int n_in,
                              void* d_out, int out_size, void* d_ws, size_t ws_size,
                              hipStream_t stream) {
  const float* mem = (const float*)d_in[0];
  const float* key = (const float*)d_in[1];
  const float* val = (const float*)d_in[2];
  float* out = (float*)d_out;
  sgm_kernel<<<B_, 256, 0, stream>>>(mem, key, val, out);
}

// Round 11
// 980.153 us; speedup vs baseline: 1.8621x; 1.0459x over previous
//
#include <hip/hip_runtime.h>
#include <math.h>

#define B_   64
#define S_   1024
#define DK_  128
#define DV_  128
#define LR_    0.1f
#define THR_   0.1f
#define ITEMP_ 10.0f   // 1/temperature
#define EPS_   1e-6f

// ---- DPP wave reduction helpers ----
template<int CTRL>
__device__ __forceinline__ float dpp_add(float x) {
  int t = __builtin_amdgcn_update_dpp(0, __float_as_int(x), CTRL, 0xf, 0xf, true);
  return x + __int_as_float(t);
}
__device__ __forceinline__ float wave_sum64(float x) {
  x = dpp_add<0x111>(x); // row_shr:1
  x = dpp_add<0x112>(x); // row_shr:2
  x = dpp_add<0x114>(x); // row_shr:4
  x = dpp_add<0x118>(x); // row_shr:8
  x = dpp_add<0x142>(x); // row_bcast:15
  x = dpp_add<0x143>(x); // row_bcast:31
  return __int_as_float(__builtin_amdgcn_readlane(__float_as_int(x), 63));
}
__device__ __forceinline__ float pair_sum(float x) { // 2j <-> 2j+1
  int t = __builtin_amdgcn_update_dpp(0, __float_as_int(x), 0xB1, 0xf, 0xf, true);
  return x + __int_as_float(t);
}

// ---- async global -> LDS ----
__device__ __forceinline__ void gll16(const float* g, float* l) {
  __builtin_amdgcn_global_load_lds(
      (const __attribute__((address_space(1))) unsigned int*)g,
      (__attribute__((address_space(3))) unsigned int*)l, 16, 0, 0);
}
__device__ __forceinline__ void gll4(const float* g, float* l) {
  __builtin_amdgcn_global_load_lds(
      (const __attribute__((address_space(1))) unsigned int*)g,
      (__attribute__((address_space(3))) unsigned int*)l, 4, 0, 0);
}

__global__ __launch_bounds__(256, 1)
void sgm_kernel(const float* __restrict__ mem_in,
                const float* __restrict__ key,
                const float* __restrict__ value,
                float* __restrict__ out) {
  const int b    = blockIdx.x;
  const int tid  = threadIdx.x;
  const int r    = tid >> 1;        // row 0..127
  const int h    = tid & 1;         // owns float4 chunks 2i+h (bank-disjoint pairs)
  const int lane = tid & 63;
  const int wv   = tid >> 6;
  const int rl   = (tid >> 1) & 31;

  __shared__ float  ldsK[4][8][DK_];   // [wave][ring8][128]
  __shared__ float  ldsV[4][8][32];
  __shared__ float4 slotS[2];          // [parity] -> 4 wave partials
  __shared__ float  gateL[S_];

  float m[64], kE[64], kO[64];
  {
    const float4* mp4 = reinterpret_cast<const float4*>(mem_in + ((size_t)b*DV_ + r)*DK_);
    #pragma unroll
    for (int i = 0; i < 16; ++i) {
      float4 t = mp4[2*i + h];
      m[4*i+0]=t.x; m[4*i+1]=t.y; m[4*i+2]=t.z; m[4*i+3]=t.w;
    }
  }
  #pragma unroll
  for (int i = 0; i < 64; ++i) kE[i] = 0.f;   // k_{-1} (a1=0, NaN-safe)

  const float* kb = key   + (size_t)b * S_ * DK_;
  const float* vb = value + (size_t)b * S_ * DV_;

  auto stage = [&](int j) {   // load step j into ring slot j&7 (per-wave copy)
    const int sl = j & 7;
    if (lane < 32) {
      gll16(kb + (size_t)j*DK_ + lane*4, &ldsK[wv][sl][0]);
      gll4 (vb + (size_t)j*DV_ + wv*32 + lane, &ldsV[wv][sl][0]);
    }
  };

  // prologue: stage steps 0..3, drain once
  stage(0); stage(1); stage(2); stage(3);
  asm volatile("s_waitcnt vmcnt(0)" ::: "memory");

  float kaC = ldsK[wv][0][lane], kbC = ldsK[wv][0][64+lane];
  float vCur = ldsV[wv][0][rl];
  float rinCur = 1.0f / (sqrtf(wave_sum64(kaC*kaC + kbC*kbC)) + EPS_);
  float rawCur;
  {
    const float4* kp4 = reinterpret_cast<const float4*>(&ldsK[wv][0][0]);
    float d0=0,d1=0,d2=0,d3=0;
    #pragma unroll
    for (int i = 0; i < 16; ++i) {
      float4 t = kp4[2*i + h];
      kO[4*i+0]=t.x; kO[4*i+1]=t.y; kO[4*i+2]=t.z; kO[4*i+3]=t.w;  // k_0
      d0=fmaf(m[4*i+0],t.x,d0); d1=fmaf(m[4*i+1],t.y,d1);
      d2=fmaf(m[4*i+2],t.z,d2); d3=fmaf(m[4*i+3],t.w,d3);
    }
    rawCur = pair_sum((d0+d1)+(d2+d3));   // M_init . k_0
  }
  float dkCur = 0.f, u1 = 0.f, gPrev = 0.f, rinPrev = 0.f;

  // step s: entry rawCur=M_{s-2}.k_s, dkCur=k_{s-1}.k_s, buf=k_{s-1}; exit buf=k_{s+1}
  auto half = [&](int s, float (&buf)[64]) {
    // ---- head (short chain from g_{s-1}) ----
    const float c1   = gPrev * rinPrev;
    const float pred = rinCur * fmaf(-(c1 * dkCur), u1, rawCur);
    const float surp = pred - vCur;
    const float ws   = wave_sum64(surp * surp);
    if (lane == 0) ((float*)&slotS[s & 1])[wv] = ws;
    const float uNew = fmaf(LR_, surp, pred);
    const float a1   = c1 * u1;
    asm volatile("s_waitcnt lgkmcnt(0)" ::: "memory");
    __builtin_amdgcn_s_barrier();                    // raw: vmcnt stays in flight
    asm volatile("" ::: "memory");
    const float4 qv = slotS[s & 1];                  // latency hides under update

    // ---- update m for step s-1 (register-only; independent of qv) ----
    #pragma unroll
    for (int i = 0; i < 64; ++i) m[i] = fmaf(-a1, buf[i], m[i]);

    const float s2 = 0.5f * ((qv.x + qv.y) + (qv.z + qv.w)); // fixed order
    const float g  = 1.0f / (1.0f + __expf((THR_ - sqrtf(s2)) * ITEMP_));
    if (tid == 0) gateL[s] = g;

    // ---- batched staging (keeps loads old at any forced wait point) ----
    if ((s & 3) == 0) {
      asm volatile("s_waitcnt vmcnt(0)" ::: "memory");   // covers 4-step-old group
      const int t0 = s+4>S_-1?S_-1:s+4, t1 = s+5>S_-1?S_-1:s+5;
      const int t2 = s+6>S_-1?S_-1:s+6, t3 = s+7>S_-1?S_-1:s+7;
      stage(t0); stage(t1); stage(t2); stage(t3);
    } else if ((s & 3) == 3) {
      asm volatile("s_waitcnt vmcnt(6)" ::: "memory");   // oldest pair of batch done
    }

    // ---- next-step scalars + matvec raw_{s+1} = M_{s-1}.k_{s+1} ----
    const int ns = (s + 1) & 7;
    const float kaN = ldsK[wv][ns][lane], kbN = ldsK[wv][ns][64+lane];
    const float vN  = ldsV[wv][ns][rl];
    const float dkN  = wave_sum64(kaC*kaN + kbC*kbN);
    const float rinN = 1.0f / (sqrtf(wave_sum64(kaN*kaN + kbN*kbN)) + EPS_);

    const float4* kp4 = reinterpret_cast<const float4*>(&ldsK[wv][ns][0]);
    float d0=0,d1=0,d2=0,d3=0;
    #pragma unroll
    for (int i = 0; i < 16; ++i) {
      float4 t = kp4[2*i + h];                       // pair-broadcast, conflict-free
      buf[4*i+0]=t.x; buf[4*i+1]=t.y; buf[4*i+2]=t.z; buf[4*i+3]=t.w;
      d0=fmaf(m[4*i+0],t.x,d0); d1=fmaf(m[4*i+1],t.y,d1);
      d2=fmaf(m[4*i+2],t.z,d2); d3=fmaf(m[4*i+3],t.w,d3);
    }
    const float rawN = pair_sum((d0+d1)+(d2+d3));

    gPrev = g; rinPrev = rinCur; rinCur = rinN; dkCur = dkN; rawCur = rawN;
    u1 = uNew; kaC = kaN; kbC = kbN; vCur = vN;
  };

  for (int s = 0; s < S_; s += 2) { half(s, kE); half(s + 1, kO); }

  // final pending update for step S-1: k_{1023} lives in ring slot 7
  {
    const float a1f = (gPrev * rinPrev) * u1;
    const float4* kp4 = reinterpret_cast<const float4*>(&ldsK[wv][7][0]);
    #pragma unroll
    for (int i = 0; i < 16; ++i) {
      float4 t = kp4[2*i + h];
      m[4*i+0]=fmaf(-a1f,t.x,m[4*i+0]); m[4*i+1]=fmaf(-a1f,t.y,m[4*i+1]);
      m[4*i+2]=fmaf(-a1f,t.z,m[4*i+2]); m[4*i+3]=fmaf(-a1f,t.w,m[4*i+3]);
    }
  }

  __syncthreads();

  float4* op4 = reinterpret_cast<float4*>(out + ((size_t)b*DV_ + r)*DK_);
  #pragma unroll
  for (int i = 0; i < 16; ++i)
    op4[2*i + h] = make_float4(m[4*i+0], m[4*i+1], m[4*i+2], m[4*i+3]);

  float* go = out + (size_t)B_ * DV_ * DK_ + (size_t)b * S_;
  reinterpret_cast<float4*>(go)[tid] = reinterpret_cast<const float4*>(gateL)[tid];
}

extern "C" void kernel_launch(void* const* d_in, const int* in_sizes, int n_in,
                              void* d_out, int out_size, void* d_ws, size_t ws_size,
                              hipStream_t stream) {
  const float* mem = (const float*)d_in[0];
  const float* key = (const float*)d_in[1];
  const float* val = (const float*)d_in[2];
  float* out = (float*)d_out;
  sgm_kernel<<<B_, 256, 0, stream>>>(mem, key, val, out);
}

// Round 12
// 850.312 us; speedup vs baseline: 2.1464x; 1.1527x over previous
//
#include <hip/hip_runtime.h>
#include <math.h>

#define B_   64
#define S_   1024
#define DK_  128
#define DV_  128
#define LR_    0.1f
#define THR_   0.1f
#define ITEMP_ 10.0f   // 1/temperature
#define EPS_   1e-6f

// ---- DPP wave reduction helpers ----
template<int CTRL>
__device__ __forceinline__ float dpp_add(float x) {
  int t = __builtin_amdgcn_update_dpp(0, __float_as_int(x), CTRL, 0xf, 0xf, true);
  return x + __int_as_float(t);
}
__device__ __forceinline__ float wave_sum64(float x) {
  x = dpp_add<0x111>(x); // row_shr:1
  x = dpp_add<0x112>(x); // row_shr:2
  x = dpp_add<0x114>(x); // row_shr:4
  x = dpp_add<0x118>(x); // row_shr:8
  x = dpp_add<0x142>(x); // row_bcast:15
  x = dpp_add<0x143>(x); // row_bcast:31
  return __int_as_float(__builtin_amdgcn_readlane(__float_as_int(x), 63));
}
__device__ __forceinline__ float quad_sum4(float x) { // all 4 quad lanes -> quad sum
  x = dpp_add<0xB1>(x);  // quad_perm [1,0,3,2]
  x = dpp_add<0x4E>(x);  // quad_perm [2,3,0,1]
  return x;
}

// ---- async global -> LDS ----
__device__ __forceinline__ void gll16(const float* g, float* l) {
  __builtin_amdgcn_global_load_lds(
      (const __attribute__((address_space(1))) unsigned int*)g,
      (__attribute__((address_space(3))) unsigned int*)l, 16, 0, 0);
}

__global__ __launch_bounds__(512, 2)
void sgm_kernel(const float* __restrict__ mem_in,
                const float* __restrict__ key,
                const float* __restrict__ value,
                float* __restrict__ out) {
  const int b    = blockIdx.x;
  const int tid  = threadIdx.x;
  const int r    = tid >> 2;        // row 0..127
  const int q    = tid & 3;         // owns float4 chunks 4i+q (bank-disjoint)
  const int lane = tid & 63;
  const int wv   = tid >> 6;        // wave 0..7

  __shared__ float ldsK[8][DK_];    // shared ring (staged by wave 0)
  __shared__ float ldsV[8][DV_];    // shared ring (staged by wave 1)
  __shared__ float slotS[2][8];     // [parity][wave] ws partials
  __shared__ float gateL[S_];

  float m[32], kE[32], kO[32];
  {
    const float4* mp4 = reinterpret_cast<const float4*>(mem_in + ((size_t)b*DV_ + r)*DK_);
    #pragma unroll
    for (int i = 0; i < 8; ++i) {
      float4 t = mp4[4*i + q];
      m[4*i+0]=t.x; m[4*i+1]=t.y; m[4*i+2]=t.z; m[4*i+3]=t.w;
    }
  }
  #pragma unroll
  for (int i = 0; i < 32; ++i) kE[i] = 0.f;   // k_{-1} (a1=0, NaN-safe)

  const float* kb = key   + (size_t)b * S_ * DK_;
  const float* vb = value + (size_t)b * S_ * DV_;

  auto stageK = [&](int j) {  // 512B: 32 lanes x 16B, linear LDS dest
    if (wv == 0 && lane < 32) gll16(kb + (size_t)j*DK_ + lane*4, &ldsK[j & 7][0]);
  };
  auto stageV = [&](int j) {
    if (wv == 1 && lane < 32) gll16(vb + (size_t)j*DV_ + lane*4, &ldsV[j & 7][0]);
  };

  // prologue: stage steps 0..3, drain, full sync
  stageK(0); stageK(1); stageK(2); stageK(3);
  stageV(0); stageV(1); stageV(2); stageV(3);
  if (wv < 2) asm volatile("s_waitcnt vmcnt(0)" ::: "memory");
  __syncthreads();

  float kaC = ldsK[0][lane], kbC = ldsK[0][64+lane];
  float vCur = ldsV[0][r];
  float rinCur = 1.0f / (sqrtf(wave_sum64(kaC*kaC + kbC*kbC)) + EPS_);
  float rawCur;
  {
    const float4* kp4 = reinterpret_cast<const float4*>(&ldsK[0][0]);
    float d0=0,d1=0,d2=0,d3=0;
    #pragma unroll
    for (int i = 0; i < 8; ++i) {
      float4 t = kp4[4*i + q];
      kO[4*i+0]=t.x; kO[4*i+1]=t.y; kO[4*i+2]=t.z; kO[4*i+3]=t.w;  // k_0
      d0=fmaf(m[4*i+0],t.x,d0); d1=fmaf(m[4*i+1],t.y,d1);
      d2=fmaf(m[4*i+2],t.z,d2); d3=fmaf(m[4*i+3],t.w,d3);
    }
    rawCur = quad_sum4((d0+d1)+(d2+d3));   // M_init . k_0 (full row, all quad lanes)
  }
  float dkCur = 0.f, u1 = 0.f, gPrev = 0.f, rinPrev = 0.f;

  // step s: entry m=M_{s-2}, rawCur=M_{s-2}.k_s, buf=k_{s-1}; exit buf=k_{s+1}
  auto half = [&](int s, float (&buf)[32]) {
    // ---- head ----
    const float c1   = gPrev * rinPrev;
    const float pred = rinCur * fmaf(-(c1 * dkCur), u1, rawCur);
    const float surp = pred - vCur;
    const float ws   = wave_sum64(surp * surp);
    if (lane == 0) slotS[s & 1][wv] = ws;
    const float uNew = fmaf(LR_, surp, pred);
    const float a1   = c1 * u1;
    if (((s & 3) == 3) && wv < 2)
      asm volatile("s_waitcnt vmcnt(0)" ::: "memory");  // batch issued at s-3 done
    asm volatile("s_waitcnt lgkmcnt(0)" ::: "memory");
    __builtin_amdgcn_s_barrier();                       // raw: vmcnt stays in flight
    asm volatile("" ::: "memory");

    // issue slot reads first; their latency hides under the update FMAs
    const float4 p0 = *reinterpret_cast<const float4*>(&slotS[s & 1][0]);
    const float4 p1 = *reinterpret_cast<const float4*>(&slotS[s & 1][4]);
    #pragma unroll
    for (int i = 0; i < 32; ++i) m[i] = fmaf(-a1, buf[i], m[i]);  // update s-1
    const float s2 = 0.25f * (((p0.x+p0.y)+(p0.z+p0.w)) + ((p1.x+p1.y)+(p1.z+p1.w)));
    const float g  = 1.0f / (1.0f + __expf((THR_ - sqrtf(s2)) * ITEMP_));
    if (tid == 0) gateL[s] = g;

    // ---- tail: next-step scalars + matvec raw_{s+1} = M_{s-1}.k_{s+1} ----
    const int ns = (s + 1) & 7;
    const float kaN = ldsK[ns][lane], kbN = ldsK[ns][64+lane];
    const float vN  = ldsV[ns][r];
    const float dkN  = wave_sum64(kaC*kaN + kbC*kbN);
    const float rinN = 1.0f / (sqrtf(wave_sum64(kaN*kaN + kbN*kbN)) + EPS_);

    const float4* kp4 = reinterpret_cast<const float4*>(&ldsK[ns][0]);
    float d0=0,d1=0,d2=0,d3=0;
    #pragma unroll
    for (int i = 0; i < 8; ++i) {
      float4 t = kp4[4*i + q];                 // quad-broadcast, conflict-free
      buf[4*i+0]=t.x; buf[4*i+1]=t.y; buf[4*i+2]=t.z; buf[4*i+3]=t.w;
      d0=fmaf(m[4*i+0],t.x,d0); d1=fmaf(m[4*i+1],t.y,d1);
      d2=fmaf(m[4*i+2],t.z,d2); d3=fmaf(m[4*i+3],t.w,d3);
    }
    const float rawN = quad_sum4((d0+d1)+(d2+d3));

    // ---- staging batch at very end (loads stay old at any forced wait) ----
    if ((s & 3) == 0) {
      const int t0 = s+4 > S_-1 ? S_-1 : s+4, t1 = s+5 > S_-1 ? S_-1 : s+5;
      const int t2 = s+6 > S_-1 ? S_-1 : s+6, t3 = s+7 > S_-1 ? S_-1 : s+7;
      stageK(t0); stageK(t1); stageK(t2); stageK(t3);
      stageV(t0); stageV(t1); stageV(t2); stageV(t3);
    }

    gPrev = g; rinPrev = rinCur; rinCur = rinN; dkCur = dkN; rawCur = rawN;
    u1 = uNew; kaC = kaN; kbC = kbN; vCur = vN;
  };

  for (int s = 0; s < S_; s += 2) { half(s, kE); half(s + 1, kO); }

  // final pending update for step S-1: k_{1023} lives in ring slot 7
  {
    const float a1f = (gPrev * rinPrev) * u1;
    const float4* kp4 = reinterpret_cast<const float4*>(&ldsK[7][0]);
    #pragma unroll
    for (int i = 0; i < 8; ++i) {
      float4 t = kp4[4*i + q];
      m[4*i+0]=fmaf(-a1f,t.x,m[4*i+0]); m[4*i+1]=fmaf(-a1f,t.y,m[4*i+1]);
      m[4*i+2]=fmaf(-a1f,t.z,m[4*i+2]); m[4*i+3]=fmaf(-a1f,t.w,m[4*i+3]);
    }
  }

  __syncthreads();

  float4* op4 = reinterpret_cast<float4*>(out + ((size_t)b*DV_ + r)*DK_);
  #pragma unroll
  for (int i = 0; i < 8; ++i)
    op4[4*i + q] = make_float4(m[4*i+0], m[4*i+1], m[4*i+2], m[4*i+3]);

  float* go = out + (size_t)B_ * DV_ * DK_ + (size_t)b * S_;
  reinterpret_cast<float2*>(go)[tid] = reinterpret_cast<const float2*>(gateL)[tid];
}

extern "C" void kernel_launch(void* const* d_in, const int* in_sizes, int n_in,
                              void* d_out, int out_size, void* d_ws, size_t ws_size,
                              hipStream_t stream) {
  const float* mem = (const float*)d_in[0];
  const float* key = (const float*)d_in[1];
  const float* val = (const float*)d_in[2];
  float* out = (float*)d_out;
  sgm_kernel<<<B_, 512, 0, stream>>>(mem, key, val, out);
}